// Round 9
// baseline (348.691 us; speedup 1.0000x reference)
//
#include <hip/hip_runtime.h>
#include <hip/hip_bf16.h>
#include <cstdint>
#include <cstddef>

#define SEQ 2048
#define DM  1024

typedef __attribute__((ext_vector_type(8))) __bf16 bf16x8;
typedef __attribute__((ext_vector_type(4))) float  f32x4;
using bf16 = __hip_bfloat16;

// ---------------------------------------------------------------- helpers
__device__ __forceinline__ void gload_lds16(const bf16* g, bf16* l) {
  __builtin_amdgcn_global_load_lds((const __attribute__((address_space(1))) void*)g,
                                   (__attribute__((address_space(3))) void*)l,
                                   16, 0, 0);
}

// XCD-chunked 4x4-supertile block remap (bijective: NWG%8==0, GM%4==0, GN%4==0).
template <int GM, int GN>
__device__ __forceinline__ void remap_wg(int id, int& bm, int& bn) {
  constexpr int NWG = GM * GN;
  constexpr int CPX = NWG / 8;
  id = (id & 7) * CPX + (id >> 3);
  const int st = id >> 4, wi = id & 15;
  constexpr int STM = GM / 4;
  bm = (st % STM) * 4 + (wi & 3);
  bn = (st / STM) * 4 + (wi >> 2);
}

// ---------------------------------------------------------------- transpose fp32(KxN) -> bf16(NxK)
__global__ void transpose_to_bf16(const float* __restrict__ in, bf16* __restrict__ out,
                                  int K, int N) {
  __shared__ float tile[32][33];
  const int k0 = blockIdx.y * 32, n0 = blockIdx.x * 32;
  const int tx = threadIdx.x, ty = threadIdx.y;
#pragma unroll
  for (int i = ty; i < 32; i += 8)
    tile[i][tx] = in[(size_t)(k0 + i) * N + n0 + tx];
  __syncthreads();
#pragma unroll
  for (int i = ty; i < 32; i += 8)
    out[(size_t)(n0 + i) * K + k0 + tx] = __float2bfloat16(tile[tx][i]);
}

// ---------------------------------------------------------------- layernorm fp32 row -> bf16
__global__ void ln_to_bf16(const float* __restrict__ x, const float* __restrict__ g,
                           const float* __restrict__ bt, bf16* __restrict__ out) {
  const int row = blockIdx.x;
  const float4 v = ((const float4*)(x + (size_t)row * DM))[threadIdx.x];
  float s  = v.x + v.y + v.z + v.w;
  float s2 = v.x * v.x + v.y * v.y + v.z * v.z + v.w * v.w;
#pragma unroll
  for (int o = 32; o > 0; o >>= 1) { s += __shfl_down(s, o); s2 += __shfl_down(s2, o); }
  __shared__ float red[8];
  const int wave = threadIdx.x >> 6, lane = threadIdx.x & 63;
  if (lane == 0) { red[wave] = s; red[4 + wave] = s2; }
  __syncthreads();
  s  = red[0] + red[1] + red[2] + red[3];
  s2 = red[4] + red[5] + red[6] + red[7];
  const float mu  = s * (1.f / DM);
  const float var = s2 * (1.f / DM) - mu * mu;
  const float r   = rsqrtf(var + 1e-5f);
  const float4 gv = ((const float4*)g)[threadIdx.x];
  const float4 bv = ((const float4*)bt)[threadIdx.x];
  bf16* o = out + (size_t)row * DM + threadIdx.x * 4;
  o[0] = __float2bfloat16((v.x - mu) * r * gv.x + bv.x);
  o[1] = __float2bfloat16((v.y - mu) * r * gv.y + bv.y);
  o[2] = __float2bfloat16((v.z - mu) * r * gv.z + bv.z);
  o[3] = __float2bfloat16((v.w - mu) * r * gv.w + bv.w);
}

// ---------------------------------------------------------------- GEMM: C = A(MxK) @ Bt(NxK)^T + bias
// 128x128 tiles, BK=32, double-buffered single-barrier K-loop + supertile/XCD
// remap. Epilogue: LDS-staged full-line bf16 stores (scalar bf16 stores were
// 32B partial lines -> L2 RMW: FETCH +21MB, WRITE 72MB vs 32MB data).
// QKV V-blocks (n0>=2048, block-uniform) keep the direct transposed vt path.
enum { EP_BF16 = 0, EP_GELU = 1, EP_RESID = 2, EP_QKV = 3 };

template <int MODE, int TM, int TN, int GM, int GN>
__global__ void gemm_bt(const bf16* __restrict__ A, const bf16* __restrict__ Bt,
                        const float* __restrict__ bias, const float* __restrict__ resid,
                        float* __restrict__ Cf, bf16* __restrict__ Cb, bf16* __restrict__ vt,
                        int M, int N, int K) {
  constexpr int ABUF = TM * 32;
  constexpr int BBUF = TN * 32;
  constexpr int MI = TM / 32;
  constexpr int NI = TN / 32;
  // single allocation: K-loop uses [As|Bs]; epilogue reuses it as 128x128 C-stage
  __shared__ __attribute__((aligned(16))) bf16 smem[2 * ABUF + 2 * BBUF];
  bf16* As = smem;
  bf16* Bs = smem + 2 * ABUF;
  const int tid  = threadIdx.x;
  const int wave = tid >> 6, lane = tid & 63;
  const int l16 = lane & 15, lq = lane >> 4;
  int bm, bn;
  remap_wg<GM, GN>(blockIdx.x, bm, bn);
  const int m0 = bm * TM, n0 = bn * TN;
  const int wr = (wave >> 1) * (TM / 2), wc = (wave & 1) * (TN / 2);

  f32x4 acc[MI][NI];
#pragma unroll
  for (int i = 0; i < MI; i++)
#pragma unroll
    for (int j = 0; j < NI; j++) acc[i][j] = 0;

  const int srow = tid >> 2;
  const int scol = (tid & 3) * 8;
  const bf16* ga = A  + (size_t)(m0 + srow) * K + scol;
  const bf16* gb = Bt + (size_t)(n0 + srow) * K + scol;

  // stage tile 0 -> buffer 0
  {
    bf16* la = As + wave * 512;
    bf16* lb = Bs + wave * 512;
    gload_lds16(ga, la);
    if (TM == 128) gload_lds16(ga + (size_t)64 * K, la + 2048);
    gload_lds16(gb, lb);
    if (TN == 128) gload_lds16(gb + (size_t)64 * K, lb + 2048);
  }

  const int NKT = K >> 5;
  for (int it = 0; it < NKT; ++it) {
    __syncthreads();  // drains tile-it loads (only ones outstanding); aligns waves
    const int cur = it & 1, nxt = cur ^ 1;
    if (it + 1 < NKT) {  // async-stage tile it+1; overlaps MFMA below
      const int kt = (it + 1) << 5;
      bf16* la = As + nxt * ABUF + wave * 512;
      bf16* lb = Bs + nxt * BBUF + wave * 512;
      gload_lds16(ga + kt, la);
      if (TM == 128) gload_lds16(ga + (size_t)64 * K + kt, la + 2048);
      gload_lds16(gb + kt, lb);
      if (TN == 128) gload_lds16(gb + (size_t)64 * K + kt, lb + 2048);
    }
    bf16x8 af[MI], bfr[NI];
#pragma unroll
    for (int mi = 0; mi < MI; mi++)
      af[mi] = *(const bf16x8*)(As + cur * ABUF + (wr + mi * 16 + l16) * 32 + lq * 8);
#pragma unroll
    for (int ni = 0; ni < NI; ni++)
      bfr[ni] = *(const bf16x8*)(Bs + cur * BBUF + (wc + ni * 16 + l16) * 32 + lq * 8);
#pragma unroll
    for (int mi = 0; mi < MI; mi++)
#pragma unroll
      for (int ni = 0; ni < NI; ni++)
        acc[mi][ni] = __builtin_amdgcn_mfma_f32_16x16x32_bf16(af[mi], bfr[ni], acc[mi][ni], 0, 0, 0);
  }

  // ---------------- epilogue ----------------
  if (MODE == EP_QKV && n0 >= 2048) {
    // V-block: direct transposed write vt[b][hd][t] (4 contiguous t per lane)
#pragma unroll
    for (int ni = 0; ni < NI; ni++) {
      const int col = n0 + wc + ni * 16 + l16;
      const float bb = bias[col];
#pragma unroll
      for (int mi = 0; mi < MI; mi++) {
        const int row0 = m0 + wr + mi * 16 + lq * 4;
        __attribute__((aligned(8))) bf16 pk[4];
#pragma unroll
        for (int r = 0; r < 4; r++) pk[r] = __float2bfloat16(acc[mi][ni][r] + bb);
        *(uint2*)(vt + (size_t)((row0 >> 11) * 1024 + (col - 2048)) * SEQ + (row0 & 2047)) =
            *(const uint2*)pk;
      }
    }
  } else {
    __syncthreads();  // K-loop LDS reads complete in all waves; smem reusable
    // stage C tile into smem[row][col ^ q<<3], q=(row>>2)&7 (bank spread ~2-way;
    // XOR keeps 8-col/16B blocks contiguous for the vector readback)
#pragma unroll
    for (int ni = 0; ni < NI; ni++) {
      const int coll = wc + ni * 16 + l16;
      const float bb = bias[n0 + coll];
#pragma unroll
      for (int mi = 0; mi < MI; mi++) {
#pragma unroll
        for (int r = 0; r < 4; r++) {
          const int row = wr + mi * 16 + lq * 4 + r;
          float v = acc[mi][ni][r] + bb;
          if (MODE == EP_GELU) v = 0.5f * v * (1.0f + erff(v * 0.70710678118654752f));
          smem[row * TN + (coll ^ (((row >> 2) & 7) << 3))] = __float2bfloat16(v);
        }
      }
    }
    __syncthreads();
    // write back: full 256B rows, 16B/thread, 8 passes -> complete 64B lines
    const int rrow = tid >> 4;          // 0..15
    const int cblk = (tid & 15) * 8;    // 16B block
#pragma unroll
    for (int p = 0; p < 8; p++) {
      const int row = p * 16 + rrow;
      const int q = (row >> 2) & 7;
      const uint4 val = *(const uint4*)(smem + row * TN + (cblk ^ (q << 3)));
      *(uint4*)(Cb + (size_t)(m0 + row) * N + n0 + cblk) = val;
    }
  }
}

// ---------------------------------------------------------------- thin-N GEMM: 64x64 tile, BK=64 (round-3 proven)
// XOR-swizzled LDS (linear gload_lds dest + pre-swizzled global source + same
// XOR on ds_read_b128); 16 MFMA/wave per barrier. + supertile/XCD remap.
// f32 scalar stores are already full-line (16 lanes x 4B = 64B) - no change.
template <int GM, int GN>
__global__ __launch_bounds__(256, 4)
void gemm_bt64(const bf16* __restrict__ A, const bf16* __restrict__ Bt,
               const float* __restrict__ bias, const float* __restrict__ resid,
               float* __restrict__ Cf, int M, int N, int K) {
  constexpr int TILE = 64 * 64;  // 4096 elems = 8KB
  __shared__ __attribute__((aligned(16))) bf16 As[2 * TILE];
  __shared__ __attribute__((aligned(16))) bf16 Bs[2 * TILE];
  const int tid  = threadIdx.x;
  const int wave = tid >> 6, lane = tid & 63;
  const int l16 = lane & 15, lq = lane >> 4;
  int bm, bn;
  remap_wg<GM, GN>(blockIdx.x, bm, bn);
  const int m0 = bm * 64, n0 = bn * 64;
  const int wr = (wave >> 1) * 32, wc = (wave & 1) * 32;

  f32x4 acc[2][2];
#pragma unroll
  for (int i = 0; i < 2; i++)
#pragma unroll
    for (int j = 0; j < 2; j++) acc[i][j] = 0;

  const int srow = tid >> 3;                // 0..31 (pass0); +32 pass1
  const int scb  = (tid & 7) ^ (srow & 7);  // (srow+32)&7 == srow&7
  const bf16* ga0 = A  + (size_t)(m0 + srow) * K + scb * 8;
  const bf16* ga1 = A  + (size_t)(m0 + srow + 32) * K + scb * 8;
  const bf16* gb0 = Bt + (size_t)(n0 + srow) * K + scb * 8;
  const bf16* gb1 = Bt + (size_t)(n0 + srow + 32) * K + scb * 8;
  const int ld0 = wave * 512;        // wave-uniform LDS dest (elems)
  const int ld1 = 2048 + wave * 512;

  gload_lds16(ga0, As + ld0);
  gload_lds16(ga1, As + ld1);
  gload_lds16(gb0, Bs + ld0);
  gload_lds16(gb1, Bs + ld1);

  const int sxa = l16 & 7;

  const int NKT = K >> 6;
  for (int it = 0; it < NKT; ++it) {
    __syncthreads();
    const int cur = (it & 1) * TILE;
    if (it + 1 < NKT) {
      const int nxt = ((it + 1) & 1) * TILE;
      const int kt = (it + 1) << 6;
      gload_lds16(ga0 + kt, As + nxt + ld0);
      gload_lds16(ga1 + kt, As + nxt + ld1);
      gload_lds16(gb0 + kt, Bs + nxt + ld0);
      gload_lds16(gb1 + kt, Bs + nxt + ld1);
    }
    bf16x8 af[2][2], bfv[2][2];
#pragma unroll
    for (int mi = 0; mi < 2; mi++) {
      const int row = wr + mi * 16 + l16;
#pragma unroll
      for (int kk = 0; kk < 2; kk++)
        af[mi][kk] = *(const bf16x8*)(As + cur + row * 64 + (((kk * 4 + lq) ^ sxa) << 3));
    }
#pragma unroll
    for (int ni = 0; ni < 2; ni++) {
      const int row = wc + ni * 16 + l16;
#pragma unroll
      for (int kk = 0; kk < 2; kk++)
        bfv[ni][kk] = *(const bf16x8*)(Bs + cur + row * 64 + (((kk * 4 + lq) ^ sxa) << 3));
    }
#pragma unroll
    for (int kk = 0; kk < 2; kk++)
#pragma unroll
      for (int mi = 0; mi < 2; mi++)
#pragma unroll
        for (int ni = 0; ni < 2; ni++)
          acc[mi][ni] = __builtin_amdgcn_mfma_f32_16x16x32_bf16(af[mi][kk], bfv[ni][kk],
                                                                acc[mi][ni], 0, 0, 0);
  }

#pragma unroll
  for (int ni = 0; ni < 2; ni++) {
    const int col = n0 + wc + ni * 16 + l16;
    const float bb = bias[col];
#pragma unroll
    for (int mi = 0; mi < 2; mi++) {
#pragma unroll
      for (int r = 0; r < 4; r++) {
        const int row = m0 + wr + mi * 16 + lq * 4 + r;
        const size_t idx = (size_t)row * N + col;
        Cf[idx] = resid[idx] + acc[mi][ni][r] + bb;
      }
    }
  }
}

// ---------------------------------------------------------------- flash attention v5 (causal, pair-shared; round-3 proven)
#define SCALE_LOG2 0.18033688011112042f  /* 0.125 * log2(e) */

__global__ __launch_bounds__(512, 2)
void flash_attn(const bf16* __restrict__ qkv, const bf16* __restrict__ VTg,
                bf16* __restrict__ out) {
  const int idx  = blockIdx.x;
  const int praw = idx & 15;
  const int p    = ((idx >> 8) & 1) ? (15 - praw) : praw;
  const int bh   = (idx >> 4) & 31;
  const int h    = bh & 15;
  const int b    = bh >> 4;
  const int qlow = p, qhigh = 31 - p;

  const int tid = threadIdx.x;
  const int w = tid >> 6, lane = tid & 63;
  const int wq = w & 3, hf = w >> 2;  // hf=0 -> qhigh, hf=1 -> qlow
  const int l16 = lane & 15, lq = lane >> 4;
  const int myqb = hf ? qlow : qhigh;

  const size_t base = (size_t)b * SEQ * 3072;
  const bf16* Qg = qkv + base + (size_t)h * 64;
  const bf16* Kg = qkv + base + 1024 + (size_t)h * 64;
  const bf16* Vt = VTg + (size_t)(b * 1024 + h * 64) * SEQ;  // [d][t] rows

  __shared__ __attribute__((aligned(16))) bf16 Ks[2 * 4096];
  __shared__ __attribute__((aligned(16))) bf16 VTs[2 * 4096];
  __shared__ __attribute__((aligned(16))) bf16 Ps[8 * 1024];

  const int srow = tid >> 3;                 // 0..63
  const int scb  = (tid & 7) ^ (srow & 7);
  const bf16* gK = Kg + (size_t)srow * 3072 + scb * 8;
  const bf16* gV = Vt + (size_t)srow * SEQ + scb * 8;
  const int ldst = w * 512;                  // wave-uniform LDS dest (elems)

  gload_lds16(gK, Ks + ldst);
  gload_lds16(gV, VTs + ldst);

  const bf16* qrow = Qg + (size_t)(myqb * 64 + wq * 16 + l16) * 3072 + lq * 8;
  const bf16x8 qf0 = *(const bf16x8*)(qrow);
  const bf16x8 qf1 = *(const bf16x8*)(qrow + 32);

  const int koffA = l16 * 64 + ((lq ^ (l16 & 7)) << 3);
  const int koffB = l16 * 64 + (((4 + lq) ^ (l16 & 7)) << 3);
  const int l16h = l16 >> 3;
  const int pco  = w * 1024 + (l16 & 7);

  f32x4 oacc[4];
#pragma unroll
  for (int i = 0; i < 4; i++) oacc[i] = 0;
  float lsum[4] = {0.f, 0.f, 0.f, 0.f};

  const int nkt = qhigh + 1;
  for (int kb = 0; kb < nkt; ++kb) {
    __syncthreads();  // drains tile-kb stages; separates buf reuse
    const int cur = (kb & 1) * 4096;
    if (kb + 1 < nkt) {
      const int nxt = ((kb + 1) & 1) * 4096;
      const size_t ko = (size_t)(kb + 1) * 64;
      gload_lds16(gK + ko * 3072, Ks + nxt + ldst);
      gload_lds16(gV + ko, VTs + nxt + ldst);
    }

    if (kb <= myqb) {  // wave-uniform: inactive half just meets barriers
      f32x4 sacc[4];
#pragma unroll
      for (int nt = 0; nt < 4; nt++) sacc[nt] = 0;
#pragma unroll
      for (int nt = 0; nt < 4; nt++) {
        const bf16x8 kf0 = *(const bf16x8*)(Ks + cur + nt * 1024 + koffA);
        const bf16x8 kf1 = *(const bf16x8*)(Ks + cur + nt * 1024 + koffB);
        sacc[nt] = __builtin_amdgcn_mfma_f32_16x16x32_bf16(qf0, kf0, sacc[nt], 0, 0, 0);
        sacc[nt] = __builtin_amdgcn_mfma_f32_16x16x32_bf16(qf1, kf1, sacc[nt], 0, 0, 0);
      }

      if (kb == myqb) {  // diagonal tile: masked softmax
#pragma unroll
        for (int r = 0; r < 4; r++) {
          const int rowp = lq * 4 + r;
          const int qloc = wq * 16 + rowp;
          float e[4];
#pragma unroll
          for (int nt = 0; nt < 4; nt++) {
            float sv = sacc[nt][r] * SCALE_LOG2;
            sv = fminf(sv, 88.f);
            if (nt * 16 + l16 > qloc) sv = -1e30f;
            e[nt] = exp2f(sv);
            Ps[pco + rowp * 64 + ((((nt * 2 + l16h)) ^ (rowp & 7)) << 3)] = __float2bfloat16(e[nt]);
          }
          lsum[r] += (e[0] + e[1]) + (e[2] + e[3]);
        }
      } else {
#pragma unroll
        for (int r = 0; r < 4; r++) {
          const int rowp = lq * 4 + r;
          float e[4];
#pragma unroll
          for (int nt = 0; nt < 4; nt++) {
            float sv = sacc[nt][r] * SCALE_LOG2;
            sv = fminf(sv, 88.f);
            e[nt] = exp2f(sv);
            Ps[pco + rowp * 64 + ((((nt * 2 + l16h)) ^ (rowp & 7)) << 3)] = __float2bfloat16(e[nt]);
          }
          lsum[r] += (e[0] + e[1]) + (e[2] + e[3]);
        }
      }

      const bf16x8 pf0 = *(const bf16x8*)(Ps + w * 1024 + koffA);
      const bf16x8 pf1 = *(const bf16x8*)(Ps + w * 1024 + koffB);
#pragma unroll
      for (int dt = 0; dt < 4; dt++) {
        const bf16x8 vf0 = *(const bf16x8*)(VTs + cur + dt * 1024 + koffA);
        const bf16x8 vf1 = *(const bf16x8*)(VTs + cur + dt * 1024 + koffB);
        oacc[dt] = __builtin_amdgcn_mfma_f32_16x16x32_bf16(pf0, vf0, oacc[dt], 0, 0, 0);
        oacc[dt] = __builtin_amdgcn_mfma_f32_16x16x32_bf16(pf1, vf1, oacc[dt], 0, 0, 0);
      }
    }
  }

#pragma unroll
  for (int r = 0; r < 4; r++) {
    float l = lsum[r];
    l += __shfl_xor(l, 1);
    l += __shfl_xor(l, 2);
    l += __shfl_xor(l, 4);
    l += __shfl_xor(l, 8);
    lsum[r] = 1.f / l;
  }
#pragma unroll
  for (int dt = 0; dt < 4; dt++)
#pragma unroll
    for (int r = 0; r < 4; r++) {
      const int qrow_ = myqb * 64 + wq * 16 + lq * 4 + r;
      const float v = oacc[dt][r] * lsum[r];
      out[(size_t)(b * SEQ + qrow_) * DM + h * 64 + dt * 16 + l16] = __float2bfloat16(v);
    }
}

// ---------------------------------------------------------------- launch
extern "C" void kernel_launch(void* const* d_in, const int* in_sizes, int n_in,
                              void* d_out, int out_size, void* d_ws, size_t ws_size,
                              hipStream_t stream) {
  const float* x     = (const float*)d_in[0];
  const float* w_qkv = (const float*)d_in[1];
  const float* b_qkv = (const float*)d_in[2];
  const float* w_fc  = (const float*)d_in[3];
  const float* b_fc  = (const float*)d_in[4];
  const float* ln1_g = (const float*)d_in[5];
  const float* ln1_b = (const float*)d_in[6];
  const float* ln2_g = (const float*)d_in[7];
  const float* ln2_b = (const float*)d_in[8];
  const float* w1    = (const float*)d_in[9];
  const float* b1    = (const float*)d_in[10];
  const float* w2    = (const float*)d_in[11];
  const float* b2    = (const float*)d_in[12];
  float* out = (float*)d_out;

  char* ws    = (char*)d_ws;
  float* x2   = (float*)(ws);                       // 16 MB fp32 post-attn residual
  bf16* VTg   = (bf16*)(ws);                        // 8 MB V^T [b][h][d][t] — lifetime
                                                    // [qkv-gemm .. flash], disjoint from x2
  bf16* big   = (bf16*)(ws + (size_t)(16 << 20));   // 32 MB: qkv (24MB) then fc1 out (32MB)
  bf16* small = (bf16*)(ws + (size_t)(48 << 20));   // 8 MB: h1 / attn-out / h2
  bf16* wT    = (bf16*)(ws + (size_t)(56 << 20));   // 8 MB: transposed weight scratch

  const dim3 tb(32, 8);

  ln_to_bf16<<<dim3(4096), dim3(256), 0, stream>>>(x, ln1_g, ln1_b, small);
  transpose_to_bf16<<<dim3(96, 32), tb, 0, stream>>>(w_qkv, wT, 1024, 3072);
  gemm_bt<EP_QKV, 128, 128, 32, 24><<<dim3(768), dim3(256), 0, stream>>>(
      small, wT, b_qkv, nullptr, nullptr, big, VTg, 4096, 3072, 1024);
  flash_attn<<<dim3(512), dim3(512), 0, stream>>>(big, VTg, small);
  transpose_to_bf16<<<dim3(32, 32), tb, 0, stream>>>(w_fc, wT, 1024, 1024);
  gemm_bt64<64, 16><<<dim3(1024), dim3(256), 0, stream>>>(
      small, wT, b_fc, x, x2, 4096, 1024, 1024);
  ln_to_bf16<<<dim3(4096), dim3(256), 0, stream>>>(x2, ln2_g, ln2_b, small);
  transpose_to_bf16<<<dim3(128, 32), tb, 0, stream>>>(w1, wT, 1024, 4096);
  gemm_bt<EP_GELU, 128, 128, 32, 32><<<dim3(1024), dim3(256), 0, stream>>>(
      small, wT, b1, nullptr, nullptr, big, nullptr, 4096, 4096, 1024);
  transpose_to_bf16<<<dim3(32, 128), tb, 0, stream>>>(w2, wT, 4096, 1024);
  gemm_bt64<64, 16><<<dim3(1024), dim3(256), 0, stream>>>(
      big, wT, b2, x2, out, 4096, 1024, 4096);
}